// Round 4
// baseline (513.606 us; speedup 1.0000x reference)
//
#include <hip/hip_runtime.h>

#define A_DIM 6
#define HID_D 64
#define LATENT_D 64
#define GRU_IN_D 134
#define T_STEPS 128
#define N_ENV 10
#define BN_TOT 640

typedef float f2 __attribute__((ext_vector_type(2)));

// Pre-scaled transcendentals: caller folds the log2e factors into the args.
//   sig_pre(x)  == sigmoid(t) where x = -1.4426950408889634f * t
//   tanh_pre(y) == tanh(t)    where y =  2.8853900817779268f * t
__device__ __forceinline__ float sig_pre(float x) {
    return __builtin_amdgcn_rcpf(1.0f + __builtin_amdgcn_exp2f(x));
}
__device__ __forceinline__ float tanh_pre(float y) {
    return fmaf(-2.0f, __builtin_amdgcn_rcpf(1.0f + __builtin_amdgcn_exp2f(y)), 1.0f);
}
#define KSIG (-1.4426950408889634f)
#define KTANH (2.8853900817779268f)

template<int CTRL>
__device__ __forceinline__ float dppadd(float v) {
    int t = __builtin_amdgcn_update_dpp(0, __builtin_bit_cast(int, v), CTRL, 0xf, 0xf, true);
    return v + __builtin_bit_cast(float, t);
}
// sum over all 64 lanes -> wave-uniform scalar (VALU pipe only)
__device__ __forceinline__ float wave_reduce_add(float v) {
    v = dppadd<0x111>(v);   // row_shr:1
    v = dppadd<0x112>(v);   // row_shr:2
    v = dppadd<0x114>(v);   // row_shr:4
    v = dppadd<0x118>(v);   // row_shr:8
    v = dppadd<0x142>(v);   // row_bcast:15
    v = dppadd<0x143>(v);   // row_bcast:31 -> lane 63 has total
    return __builtin_bit_cast(float, __builtin_amdgcn_readlane(__builtin_bit_cast(int, v), 63));
}

__global__ __launch_bounds__(64) __attribute__((amdgpu_waves_per_eu(1, 1)))
void policy_kernel(const float* __restrict__ s_h,
                   const int*   __restrict__ a_h,
                   const float* __restrict__ b_z,
                   const float* __restrict__ conv1_w, const float* __restrict__ conv1_b,
                   const float* __restrict__ conv2_w, const float* __restrict__ conv2_b,
                   const float* __restrict__ fc_w,    const float* __restrict__ fc_b,
                   const float* __restrict__ emb,
                   const float* __restrict__ gru_wih, const float* __restrict__ gru_whh,
                   const float* __restrict__ gru_bih, const float* __restrict__ gru_bhh,
                   const float* __restrict__ mlp1_w,  const float* __restrict__ mlp1_b,
                   const float* __restrict__ mlp2_w,  const float* __restrict__ mlp2_b,
                   float* __restrict__ logits_out, float* __restrict__ mask_out)
{
    __shared__ __align__(16) float s0[512];      // frame0 [c][h][w]
    __shared__ __align__(16) float a1[1152];     // conv1 out [32][36]
    __shared__ __align__(16) float a2[512];      // conv2 out flat
    __shared__ __align__(16) float semb[64];
    __shared__ __align__(16) float gxc[192];     // step-invariant gx (+biases)
    __shared__ __align__(16) float hspec[6*64];  // speculative h_{t+1} per action

    const int bn  = blockIdx.x;          // 0..639
    const int tid = threadIdx.x;         // 0..63 — one wave does everything
    const int j   = tid;

    // ---- masks output ----
    #pragma unroll
    for (int i = 0; i < 2; ++i) {
        const int t = tid + i * 64;
        mask_out[bn * T_STEPS + t] = (a_h[bn * T_STEPS + t] != (A_DIM - 1)) ? 1.0f : 0.0f;
    }

    // ---- load frame 0 ----
    {
        const float* src = s_h + (size_t)bn * T_STEPS * 512;
        #pragma unroll
        for (int i = 0; i < 8; ++i) s0[tid + i * 64] = src[tid + i * 64];
    }
    __syncthreads();

    // ---- conv1: (8,8,8) -> (32,6,6), ReLU ----
    for (int i = tid; i < 1152; i += 64) {
        const int oc = i / 36, r = i % 36, oh = r / 6, ow = r % 6;
        float sum = conv1_b[oc];
        const float* wp = conv1_w + oc * 72;
        #pragma unroll
        for (int ic = 0; ic < 8; ++ic)
            #pragma unroll
            for (int kh = 0; kh < 3; ++kh)
                #pragma unroll
                for (int kw = 0; kw < 3; ++kw)
                    sum = fmaf(s0[ic * 64 + (oh + kh) * 8 + (ow + kw)],
                               wp[ic * 9 + kh * 3 + kw], sum);
        a1[i] = fmaxf(sum, 0.0f);
    }
    __syncthreads();

    // ---- conv2: (32,6,6) -> (32,4,4), ReLU ----
    for (int i = tid; i < 512; i += 64) {
        const int oc = i / 16, r = i % 16, oh = r / 4, ow = r % 4;
        float sum = conv2_b[oc];
        const float* wp = conv2_w + oc * 288;
        for (int ic = 0; ic < 32; ++ic)
            #pragma unroll
            for (int kh = 0; kh < 3; ++kh)
                #pragma unroll
                for (int kw = 0; kw < 3; ++kw)
                    sum = fmaf(a1[ic * 36 + (oh + kh) * 6 + (ow + kw)],
                               wp[ic * 9 + kh * 3 + kw], sum);
        a2[i] = fmaxf(sum, 0.0f);
    }
    __syncthreads();

    // ---- fc: 512 -> 64, ReLU (full dot per lane) ----
    {
        const float* wp = fc_w + j * 512;
        float s0a = 0.f, s1a = 0.f, s2a = 0.f, s3a = 0.f;
        for (int k = 0; k < 512; k += 4) {
            s0a = fmaf(a2[k + 0], wp[k + 0], s0a);
            s1a = fmaf(a2[k + 1], wp[k + 1], s1a);
            s2a = fmaf(a2[k + 2], wp[k + 2], s2a);
            s3a = fmaf(a2[k + 3], wp[k + 3], s3a);
        }
        semb[j] = fmaxf((s0a + s1a) + (s2a + s3a) + fc_b[j], 0.0f);
    }
    __syncthreads();

    // ---- step-invariant gx ----
    {
        const float* bz = b_z + (size_t)(bn / N_ENV) * LATENT_D;
        for (int g = tid; g < 192; g += 64) {
            float sum = gru_bih[g] + ((g < 128) ? gru_bhh[g] : 0.0f);
            const float* wp = gru_wih + g * GRU_IN_D;
            for (int k = 0; k < 64; ++k) sum = fmaf(semb[k], wp[k], sum);
            for (int k = 0; k < 64; ++k) sum = fmaf(bz[k], wp[70 + k], sum);
            gxc[g] = sum;
        }
    }
    __syncthreads();

    // ---- per-lane fp32 weights, pre-scaled by the transcendental constants:
    //      wr,wz rows * KSIG (feed sigmoid args); wn,w1 rows * KTANH (feed tanh args)
    f2 wr[32], wz[32], wn[32], w1[32];
    {
        const float* pr = gru_whh + (size_t)j * 64;
        const float* pz = gru_whh + (size_t)(64 + j) * 64;
        const float* pn = gru_whh + (size_t)(128 + j) * 64;
        const float* p1 = mlp1_w + (size_t)j * 64;
        #pragma unroll
        for (int i = 0; i < 16; ++i) {
            float4 v;
            v = ((const float4*)pr)[i];
            wr[2*i] = (f2){KSIG*v.x, KSIG*v.y}; wr[2*i+1] = (f2){KSIG*v.z, KSIG*v.w};
            v = ((const float4*)pz)[i];
            wz[2*i] = (f2){KSIG*v.x, KSIG*v.y}; wz[2*i+1] = (f2){KSIG*v.z, KSIG*v.w};
            v = ((const float4*)pn)[i];
            wn[2*i] = (f2){KTANH*v.x, KTANH*v.y}; wn[2*i+1] = (f2){KTANH*v.z, KTANH*v.w};
            v = ((const float4*)p1)[i];
            w1[2*i] = (f2){KTANH*v.x, KTANH*v.y}; w1[2*i+1] = (f2){KTANH*v.z, KTANH*v.w};
        }
    }
    const float bhn_s = KTANH * gru_bhh[128 + j];   // scaled n-gate bias
    const float b1s   = KTANH * mlp1_b[j];          // scaled mlp1 bias

    // step-invariant per-action gate inputs, pre-scaled
    float arx[6], azx[6], anx[6], m2c[6], b2[6];
    {
        float wqr[6], wqz[6], wqn[6];
        #pragma unroll
        for (int q = 0; q < 6; ++q) {
            wqr[q] = gru_wih[j * GRU_IN_D + 64 + q];
            wqz[q] = gru_wih[(64 + j) * GRU_IN_D + 64 + q];
            wqn[q] = gru_wih[(128 + j) * GRU_IN_D + 64 + q];
        }
        const float gxr = gxc[j], gxz = gxc[64 + j], gxn = gxc[128 + j];
        #pragma unroll
        for (int a = 0; a < 6; ++a) {
            float sr = 0.f, sz = 0.f, sn = 0.f;
            #pragma unroll
            for (int q = 0; q < 6; ++q) {
                const float e = emb[a * 6 + q];
                sr = fmaf(e, wqr[q], sr);
                sz = fmaf(e, wqz[q], sz);
                sn = fmaf(e, wqn[q], sn);
            }
            arx[a] = KSIG * (gxr + sr);
            azx[a] = KSIG * (gxz + sz);
            anx[a] = KTANH * (gxn + sn);
            m2c[a] = mlp2_w[a * 64 + j];
            b2[a] = mlp2_b[a];
        }
    }

    // ---- seed: speculative h_1 candidates from h_0 = 0 (hr=hz=0, hn=bhn_s) ----
    float ha[6];
    #pragma unroll
    for (int a = 0; a < 6; ++a) {
        const float r = sig_pre(arx[a]);
        const float z = sig_pre(azx[a]);
        const float n = tanh_pre(fmaf(r, bhn_s, anx[a]));
        ha[a] = fmaf(z, 0.0f - n, n);            // (1-z)*n + z*0
    }
    __builtin_amdgcn_wave_barrier();
    #pragma unroll
    for (int a = 0; a < 6; ++a) hspec[a * 64 + j] = ha[a];
    __builtin_amdgcn_wave_barrier();

    int act = A_DIM - 1;
    float* lout = logits_out + (size_t)bn * (T_STEPS - 1) * A_DIM;

    // Force a single compact loop body: a partially-unrolled 127-trip body
    // overflows the 32 KiB L1I and a solo wave has nothing to hide the
    // instruction re-fetch behind (R0-R3 invariance + R2's +29% body-size
    // cost point at instruction delivery, not data memory).
    #pragma unroll 1
    for (int t = 0; t < T_STEPS - 1; ++t) {
        // critical path: act -> address -> sweep of h_{t+1} = hspec[act]
        const float4* hb = (const float4*)(hspec + (act << 6));
        // h_{t+1}[j] for this lane (for next speculative gates; off critical path)
        float hprev = ha[0];
        #pragma unroll
        for (int a = 1; a < 6; ++a) hprev = (act == a) ? ha[a] : hprev;

        // fused sweep: mlp1 (finishes first) + r/z/n dots — all weights resident
        f2 p1a = {0.f, 0.f}, p1b = {0.f, 0.f};
        f2 pr = {0.f, 0.f}, pz = {0.f, 0.f}, pn = {0.f, 0.f};
        #pragma unroll
        for (int i = 0; i < 16; ++i) {
            const float4 hv = hb[i];
            const f2 haa = (f2){hv.x, hv.y};
            const f2 hcc = (f2){hv.z, hv.w};
            p1a += haa * w1[2*i]; p1b += hcc * w1[2*i+1];
            pr += haa * wr[2*i]; pr += hcc * wr[2*i+1];
            pz += haa * wz[2*i]; pz += hcc * wz[2*i+1];
            pn += haa * wn[2*i]; pn += hcc * wn[2*i+1];
        }
        const f2 p1 = p1a + p1b;
        const float hid = tanh_pre(p1.x + p1.y + b1s);
        const float hr = pr.x + pr.y;                 // pre-scaled for sigmoid
        const float hz = pz.x + pz.y;                 // pre-scaled for sigmoid
        const float hn = pn.x + pn.y + bhn_s;         // pre-scaled for tanh

        // mlp2 via DPP wave reduction (critical path: hid -> l -> argmax)
        const float l0 = wave_reduce_add(hid * m2c[0]) + b2[0];
        const float l1 = wave_reduce_add(hid * m2c[1]) + b2[1];
        const float l2 = wave_reduce_add(hid * m2c[2]) + b2[2];
        const float l3 = wave_reduce_add(hid * m2c[3]) + b2[3];
        const float l4 = wave_reduce_add(hid * m2c[4]) + b2[4];
        const float l5 = wave_reduce_add(hid * m2c[5]) + b2[5];

        // speculative gates for ALL 6 actions (independent of argmax; fills
        // the DPP latency window). Produces candidate h_{t+2} values.
        #pragma unroll
        for (int a = 0; a < 6; ++a) {
            const float r = sig_pre(arx[a] + hr);
            const float z = sig_pre(azx[a] + hz);
            const float n = tanh_pre(fmaf(r, hn, anx[a]));
            ha[a] = fmaf(z, hprev - n, n);
        }
        __builtin_amdgcn_wave_barrier();
        #pragma unroll
        for (int a = 0; a < 6; ++a) hspec[a * 64 + j] = ha[a];
        __builtin_amdgcn_wave_barrier();

        // argmax, first-max-wins
        float best = l0; int bi = 0;
        if (l1 > best) { best = l1; bi = 1; }
        if (l2 > best) { best = l2; bi = 2; }
        if (l3 > best) { best = l3; bi = 3; }
        if (l4 > best) { best = l4; bi = 4; }
        if (l5 > best) { best = l5; bi = 5; }
        act = bi;

        if (j < A_DIM) {
            const float outv = (j == 0) ? l0 : (j == 1) ? l1 : (j == 2) ? l2
                             : (j == 3) ? l3 : (j == 4) ? l4 : l5;
            lout[t * A_DIM + j] = outv;
        }
    }
}

extern "C" void kernel_launch(void* const* d_in, const int* in_sizes, int n_in,
                              void* d_out, int out_size, void* d_ws, size_t ws_size,
                              hipStream_t stream) {
    const float* s_h     = (const float*)d_in[0];
    const int*   a_h     = (const int*)  d_in[1];
    const float* b_z     = (const float*)d_in[2];
    const float* conv1_w = (const float*)d_in[3];
    const float* conv1_b = (const float*)d_in[4];
    const float* conv2_w = (const float*)d_in[5];
    const float* conv2_b = (const float*)d_in[6];
    const float* fc_w    = (const float*)d_in[7];
    const float* fc_b    = (const float*)d_in[8];
    const float* emb     = (const float*)d_in[9];
    const float* gru_wih = (const float*)d_in[10];
    const float* gru_whh = (const float*)d_in[11];
    const float* gru_bih = (const float*)d_in[12];
    const float* gru_bhh = (const float*)d_in[13];
    const float* mlp1_w  = (const float*)d_in[14];
    const float* mlp1_b  = (const float*)d_in[15];
    const float* mlp2_w  = (const float*)d_in[16];
    const float* mlp2_b  = (const float*)d_in[17];

    float* out = (float*)d_out;
    float* logits_out = out;                                          // (B,N,127,6)
    float* mask_out   = out + (size_t)BN_TOT * (T_STEPS - 1) * A_DIM; // (B,N,128,1)

    policy_kernel<<<BN_TOT, 64, 0, stream>>>(
        s_h, a_h, b_z, conv1_w, conv1_b, conv2_w, conv2_b, fc_w, fc_b, emb,
        gru_wih, gru_whh, gru_bih, gru_bhh, mlp1_w, mlp1_b, mlp2_w, mlp2_b,
        logits_out, mask_out);
}